// Round 6
// baseline (219.235 us; speedup 1.0000x reference)
//
#include <hip/hip_runtime.h>
#include <math.h>

// MAM dense: C[m,n] = max_k(A[m,k]*W[n,k]) + min_k(A[m,k]*W[n,k]) + bias[n]
// A: [M,K] fp32, W: [N,K] fp32 (torch layout), C: [M,N]
//
// R6: LDS-free main loop. R2/R5 post-mortem (m134 constants): both were
// LDS-instruction-throughput-bound (~6-12 cyc/ds_read on the single per-CU
// LDS pipe; 1.7-2.2x more LDS-pipe cycles than VALU -> 42-44% VALU duty).
// New structure: lane = m. A pre-transposed to At4[j][m] (float4 of k=4j..4j+3)
// so per-lane A loads are coalesced dwordx2 through L2. W is block-uniform
// (8 n per block) -> scalar s_load into SGPRs (SMEM pipe). v_pk_mul_f32 pairs
// k and k+1 -> 1.5 VALU ops/product, 48 VALU + 2 VMEM + 8 SMEM per j, no LDS,
// no barriers. Grid 1024 blocks = 4 waves/SIMD.

typedef float f32x2 __attribute__((ext_vector_type(2)));

// (p0,p1) = (a.x*w.lo, a.y*w.hi), w from SGPR pair
static __device__ __forceinline__ f32x2 pkmul_sv(f32x2 a, double w) {
    f32x2 d;
    asm("v_pk_mul_f32 %0, %1, %2" : "=v"(d) : "v"(a), "s"(w));
    return d;
}
static __device__ __forceinline__ void upd(float& mx, float& mn, f32x2 p) {
    float nmx, nmn;
    asm("v_max3_f32 %0, %1, %2, %3" : "=v"(nmx) : "v"(p.x), "v"(p.y), "v"(mx));
    asm("v_min3_f32 %0, %1, %2, %3" : "=v"(nmn) : "v"(p.x), "v"(p.y), "v"(mn));
    mx = nmx;
    mn = nmn;
}

// ---- pre-pass: At4[j][m] = (A[m][4j], A[m][4j+1], A[m][4j+2], A[m][4j+3]) ----
__global__ __launch_bounds__(256) void transpose_a(
    const float* __restrict__ A, float4* __restrict__ at4, int M, int K)
{
    __shared__ float4 T[16][65];
    const int t = threadIdx.x;
    const int r = t >> 3;        // 0..31
    const int c = t & 7;         // 0..7
    const int m0 = blockIdx.y * 64;
    const int k0 = blockIdx.x * 64;

    const float4* Ar0 = (const float4*)(A + (size_t)(m0 + r) * K + k0);
    const float4* Ar1 = (const float4*)(A + (size_t)(m0 + r + 32) * K + k0);
    T[c][r]          = Ar0[c];
    T[c + 8][r]      = Ar0[c + 8];
    T[c][r + 32]     = Ar1[c];
    T[c + 8][r + 32] = Ar1[c + 8];
    __syncthreads();

    const int ml = t & 63;
    const int jq = t >> 6;       // 0..3
    const int j0 = blockIdx.x * 16;
#pragma unroll
    for (int q = 0; q < 4; ++q) {
        const int jl = jq * 4 + q;
        at4[(size_t)(j0 + jl) * M + m0 + ml] = T[jl][ml];
    }
}

// ---- main: no LDS, no barriers ----
__global__ __launch_bounds__(256) void mam_main(
    const float4* __restrict__ at4, const float* __restrict__ W,
    const float* __restrict__ bias, float* __restrict__ C,
    int M, int N, int K)
{
    const int t  = threadIdx.x;
    const int m  = blockIdx.y * 256 + t;   // lane-m, coalesced per wave
    const int n0 = blockIdx.x * 8;
    const int J  = K >> 2;                 // k-quads
    const int Kd = K >> 1;                 // doubles per W row
    const double* Wd = (const double*)W;

    float mx[8], mn[8];
#pragma unroll
    for (int i = 0; i < 8; ++i) { mx[i] = -INFINITY; mn[i] = INFINITY; }

    const char* aBase = (const char*)(at4 + m);
    const int aStride = M * 16;  // bytes per j row

    // ring depth 2: buffers hold j and j+1
    f32x2  aL[2], aH[2];
    double w01[2][8], w23[2][8];
#pragma unroll
    for (int b = 0; b < 2; ++b) {
        aL[b] = *(const f32x2*)(aBase + (size_t)b * aStride);
        aH[b] = *(const f32x2*)(aBase + (size_t)b * aStride + 8);
#pragma unroll
        for (int n = 0; n < 8; ++n) {
            w01[b][n] = Wd[(size_t)(n0 + n) * Kd + 2 * b];
            w23[b][n] = Wd[(size_t)(n0 + n) * Kd + 2 * b + 1];
        }
    }

#pragma unroll 2
    for (int j = 0; j < 254; ++j) {   // J==256: main loop leaves j=254,255 for tail
        const int b = j & 1;
        const f32x2 al = aL[b], ah = aH[b];
#pragma unroll
        for (int n = 0; n < 8; ++n) {
            upd(mx[n], mn[n], pkmul_sv(al, w01[b][n]));
            upd(mx[n], mn[n], pkmul_sv(ah, w23[b][n]));
        }
        // prefetch j+2 into the buffer just freed
        aL[b] = *(const f32x2*)(aBase + (size_t)(j + 2) * aStride);
        aH[b] = *(const f32x2*)(aBase + (size_t)(j + 2) * aStride + 8);
#pragma unroll
        for (int n = 0; n < 8; ++n) {
            w01[b][n] = Wd[(size_t)(n0 + n) * Kd + 2 * (j + 2)];
            w23[b][n] = Wd[(size_t)(n0 + n) * Kd + 2 * (j + 2) + 1];
        }
    }
#pragma unroll
    for (int j = 254; j < 256; ++j) {  // tail, no prefetch
        const int b = j & 1;
        const f32x2 al = aL[b], ah = aH[b];
#pragma unroll
        for (int n = 0; n < 8; ++n) {
            upd(mx[n], mn[n], pkmul_sv(al, w01[b][n]));
            upd(mx[n], mn[n], pkmul_sv(ah, w23[b][n]));
        }
    }

    float4 o0, o1;
    o0.x = mx[0] + mn[0] + bias[n0 + 0];
    o0.y = mx[1] + mn[1] + bias[n0 + 1];
    o0.z = mx[2] + mn[2] + bias[n0 + 2];
    o0.w = mx[3] + mn[3] + bias[n0 + 3];
    o1.x = mx[4] + mn[4] + bias[n0 + 4];
    o1.y = mx[5] + mn[5] + bias[n0 + 5];
    o1.z = mx[6] + mn[6] + bias[n0 + 6];
    o1.w = mx[7] + mn[7] + bias[n0 + 7];
    float4* Crow = (float4*)(C + (size_t)m * N + n0);
    Crow[0] = o0;
    Crow[1] = o1;
}

// ---- fallback (proven R2 kernel, 129 us) if workspace too small ----
#define BM 64
#define BN 64
#define BK 32
#define LDSW 68

__device__ __forceinline__ void mam_update_fb(float& mx, float& mn, float p0, float p1) {
    float nmx, nmn;
    asm("v_max3_f32 %0, %1, %2, %3" : "=v"(nmx) : "v"(p0), "v"(p1), "v"(mx));
    asm("v_min3_f32 %0, %1, %2, %3" : "=v"(nmn) : "v"(p0), "v"(p1), "v"(mn));
    mx = nmx;
    mn = nmn;
}

__global__ __launch_bounds__(256) void mam_fallback(
    const float* __restrict__ A, const float* __restrict__ W,
    const float* __restrict__ bias, float* __restrict__ C,
    int M, int N, int K)
{
    __shared__ float As[BK][LDSW];
    __shared__ float Ws[BK][LDSW];

    const int t  = threadIdx.x;
    const int tx = t & 15;
    const int ty = t >> 4;
    const int m0 = blockIdx.y * BM;
    const int n0 = blockIdx.x * BN;
    const int r  = t >> 3;
    const int kq = t & 7;

    const float* Aptr = A + (size_t)(m0 + r) * K + kq * 4;
    const float* Wptr = W + (size_t)(n0 + r) * K + kq * 4;

    float vmax[4][4], vmin[4][4];
#pragma unroll
    for (int i = 0; i < 4; ++i)
#pragma unroll
        for (int j = 0; j < 4; ++j) {
            vmax[i][j] = -INFINITY;
            vmin[i][j] =  INFINITY;
        }

    for (int k0 = 0; k0 < K; k0 += BK) {
        float4 a0 = *(const float4*)(Aptr);
        float4 a1 = *(const float4*)(Aptr + (size_t)32 * K);
        float4 w0 = *(const float4*)(Wptr);
        float4 w1 = *(const float4*)(Wptr + (size_t)32 * K);
        Aptr += BK;
        Wptr += BK;

        const int kk = kq * 4;
        As[kk + 0][r]      = a0.x;
        As[kk + 1][r]      = a0.y;
        As[kk + 2][r]      = a0.z;
        As[kk + 3][r]      = a0.w;
        As[kk + 0][r + 32] = a1.x;
        As[kk + 1][r + 32] = a1.y;
        As[kk + 2][r + 32] = a1.z;
        As[kk + 3][r + 32] = a1.w;

        Ws[kk + 0][r]      = w0.x;
        Ws[kk + 1][r]      = w0.y;
        Ws[kk + 2][r]      = w0.z;
        Ws[kk + 3][r]      = w0.w;
        Ws[kk + 0][r + 32] = w1.x;
        Ws[kk + 1][r + 32] = w1.y;
        Ws[kk + 2][r + 32] = w1.z;
        Ws[kk + 3][r + 32] = w1.w;

        __syncthreads();

#pragma unroll
        for (int k = 0; k < BK; k += 2) {
            float4 ta0 = *(const float4*)&As[k    ][ty * 4];
            float4 ta1 = *(const float4*)&As[k + 1][ty * 4];
            float4 tb0 = *(const float4*)&Ws[k    ][tx * 4];
            float4 tb1 = *(const float4*)&Ws[k + 1][tx * 4];

            float a0v[4] = {ta0.x, ta0.y, ta0.z, ta0.w};
            float a1v[4] = {ta1.x, ta1.y, ta1.z, ta1.w};
            float b0v[4] = {tb0.x, tb0.y, tb0.z, tb0.w};
            float b1v[4] = {tb1.x, tb1.y, tb1.z, tb1.w};

#pragma unroll
            for (int i = 0; i < 4; ++i)
#pragma unroll
                for (int j = 0; j < 4; ++j) {
                    float p0 = a0v[i] * b0v[j];
                    float p1 = a1v[i] * b1v[j];
                    mam_update_fb(vmax[i][j], vmin[i][j], p0, p1);
                }
        }
        __syncthreads();
    }

    float4 bv = *(const float4*)(bias + n0 + tx * 4);
#pragma unroll
    for (int i = 0; i < 4; ++i) {
        float4 o;
        o.x = vmax[i][0] + vmin[i][0] + bv.x;
        o.y = vmax[i][1] + vmin[i][1] + bv.y;
        o.z = vmax[i][2] + vmin[i][2] + bv.z;
        o.w = vmax[i][3] + vmin[i][3] + bv.w;
        *(float4*)(C + (size_t)(m0 + ty * 4 + i) * N + n0 + tx * 4) = o;
    }
}

extern "C" void kernel_launch(void* const* d_in, const int* in_sizes, int n_in,
                              void* d_out, int out_size, void* d_ws, size_t ws_size,
                              hipStream_t stream) {
    const float* x    = (const float*)d_in[0];
    const float* w    = (const float*)d_in[1];
    const float* bias = (const float*)d_in[2];
    float* out = (float*)d_out;

    const int N = in_sizes[2];
    const int K = in_sizes[1] / N;
    const int M = in_sizes[0] / K;

    const size_t need = (size_t)M * K * sizeof(float);  // At4: 8 MB
    const bool fast_ok = (ws_size >= need) && (K % 64 == 0) && (M % 256 == 0) &&
                         (N % 8 == 0) && (K == 1024);

    if (fast_ok) {
        float4* at4 = (float4*)d_ws;
        dim3 tg(K / 64, M / 64);   // (16, 32)
        transpose_a<<<tg, 256, 0, stream>>>(x, at4, M, K);
        dim3 mg(N / 8, M / 256);   // (128, 8) = 1024 blocks
        mam_main<<<mg, 256, 0, stream>>>(at4, w, bias, out, M, N, K);
    } else {
        dim3 grid(N / BN, M / BM);
        mam_fallback<<<grid, 256, 0, stream>>>(x, w, bias, out, M, N, K);
    }
}